// Round 18
// baseline (816.276 us; speedup 1.0000x reference)
//
#include <hip/hip_runtime.h>
#include <math.h>

#define WIDTH 192
#define KNN 12
#define G 64
#define NCELLS (G * G * G)
#define SMAX 8

// ---------- sorted-12 list of (d,idx) packed as positive doubles ----------
#define CE(a, b) { double _lo = fmin(a, b); double _hi = fmax(a, b); a = _lo; b = _hi; }
#define INSERT12(key) { \
    b11 = fmin(b11, key); \
    CE(b10, b11); CE(b9, b10); CE(b8, b9); CE(b7, b8); CE(b6, b7); \
    CE(b5, b6);  CE(b4, b5); CE(b3, b4); CE(b2, b3); CE(b1, b2); CE(b0, b1); }
#define DECL12 double b0,b1,b2,b3,b4,b5,b6,b7,b8,b9,b10,b11
#define INIT12 { b0=__hiloint2double(0x7F7FFFFF,0);  b1=__hiloint2double(0x7F7FFFFF,1); \
    b2=__hiloint2double(0x7F7FFFFF,2);  b3=__hiloint2double(0x7F7FFFFF,3); \
    b4=__hiloint2double(0x7F7FFFFF,4);  b5=__hiloint2double(0x7F7FFFFF,5); \
    b6=__hiloint2double(0x7F7FFFFF,6);  b7=__hiloint2double(0x7F7FFFFF,7); \
    b8=__hiloint2double(0x7F7FFFFF,8);  b9=__hiloint2double(0x7F7FFFFF,9); \
    b10=__hiloint2double(0x7F7FFFFF,10); b11=__hiloint2double(0x7F7FFFFF,11); }

// butterfly merge stage (verified BM16 network, virtual +inf padding)
#define MERGE_STAGE(m) { \
    double pb11 = shflx_d(b11, m), pb10 = shflx_d(b10, m), pb9 = shflx_d(b9, m); \
    double pb8  = shflx_d(b8, m),  pb7  = shflx_d(b7, m),  pb6 = shflx_d(b6, m); \
    double pb5  = shflx_d(b5, m),  pb4  = shflx_d(b4, m),  pb3 = shflx_d(b3, m); \
    double pb2  = shflx_d(b2, m),  pb1  = shflx_d(b1, m),  pb0 = shflx_d(b0, m); \
    double c12 = pb3, c13 = pb2, c14 = pb1, c15 = pb0; \
    b4 = fmin(b4, pb11); b5 = fmin(b5, pb10); b6 = fmin(b6, pb9);  b7 = fmin(b7, pb8); \
    b8 = fmin(b8, pb7);  b9 = fmin(b9, pb6);  b10 = fmin(b10, pb5); b11 = fmin(b11, pb4); \
    CE(b0, b8);  CE(b1, b9);  CE(b2, b10); CE(b3, b11); \
    CE(b4, c12); CE(b5, c13); CE(b6, c14); CE(b7, c15); \
    CE(b0, b4);  CE(b1, b5);  CE(b2, b6);  CE(b3, b7); \
    CE(b8, c12); CE(b9, c13); CE(b10, c14); CE(b11, c15); \
    CE(b0, b2);  CE(b1, b3);  CE(b4, b6);  CE(b5, b7); \
    CE(b8, b10); CE(b9, b11); \
    CE(b0, b1);  CE(b2, b3);  CE(b4, b5);  CE(b6, b7); \
    CE(b8, b9);  CE(b10, b11); }

__device__ inline unsigned encf(float f) {
    unsigned u = __float_as_uint(f);
    return (u & 0x80000000u) ? ~u : (u | 0x80000000u);
}
__device__ inline float decf(unsigned u) {
    return (u & 0x80000000u) ? __uint_as_float(u & 0x7fffffffu) : __uint_as_float(~u);
}
__device__ inline int cellc(float v, float mn, float invh) {
    int c = (int)((v - mn) * invh);
    return min(max(c, 0), G - 1);
}
__device__ inline double shflx_d(double v, int m) {
    int lo = __shfl_xor(__double2loint(v), m, 64);
    int hi = __shfl_xor(__double2hiint(v), m, 64);
    return __hiloint2double(hi, lo);
}

// exact union 12th-best across the wave (on copies; all lanes agree)
__device__ inline float wave_union_d12(
    double b0, double b1, double b2, double b3, double b4, double b5,
    double b6, double b7, double b8, double b9, double b10, double b11)
{
#pragma unroll
    for (int m = 1; m <= 32; m <<= 1) MERGE_STAGE(m)
    return __int_as_float(__double2hiint(b11));
}

// ---------------- prep: padded Fourier PE (sorted order) ---------------------
__global__ __launch_bounds__(256) void prep_kernel(
    const float4* __restrict__ sorted, const float* __restrict__ B0,
    const float* __restrict__ B1, const float* __restrict__ B2,
    float* __restrict__ pe, int n)
{
    int i = blockIdx.x * 256 + threadIdx.x;
    float4 q = sorted[i];
    float x0 = q.x, x1 = q.y, x2 = q.z;
    const float* Bm[3] = {B0, B1, B2};
    float* pr = pe + (size_t)i * 64;
#pragma unroll
    for (int m = 0; m < 3; ++m) {
        const float* B = Bm[m];
#pragma unroll
        for (int k = 0; k < 8; ++k) {
            float arg = x0 * B[k] + x1 * B[8 + k] + x2 * B[16 + k];
            pr[m * 16 + k]     = sinf(arg);
            pr[m * 16 + 8 + k] = cosf(arg);
        }
    }
    pr[48] = x0; pr[49] = x1; pr[50] = x2;
#pragma unroll
    for (int c = 51; c < 64; ++c) pr[c] = 0.0f;
}

// ---------------- precompute: fold z into biases -----------------------------
__global__ __launch_bounds__(256) void precompute_kernel(
    const float* __restrict__ z, const float* __restrict__ Wp, const float* __restrict__ bp,
    const float* __restrict__ Wg, const float* __restrict__ bg,
    const float* __restrict__ Wb, const float* __restrict__ bb,
    float* __restrict__ bias0, float* __restrict__ gammaB, float* __restrict__ betaB)
{
    __shared__ float zs[64];
    int t = threadIdx.x;
    if (t < 64) zs[t] = z[t];
    __syncthreads();
    if (t < WIDTH) {
        float acc = bp[t];
        for (int k = 0; k < 64; ++k) acc += zs[k] * Wp[(51 + k) * WIDTH + t];
        bias0[t] = acc;
        for (int l = 0; l < 4; ++l) {
            float g = bg[l * WIDTH + t];
            float b = bb[l * WIDTH + t];
            for (int k = 0; k < 64; ++k) {
                g += zs[k] * Wg[(l * 64 + k) * WIDTH + t];
                b += zs[k] * Wb[(l * 64 + k) * WIDTH + t];
            }
            gammaB[l * WIDTH + t] = g;
            betaB[l * WIDTH + t] = b;
        }
    }
}

// ---------------- grid build -------------------------------------------------
__global__ __launch_bounds__(64) void init_bbox_kernel(unsigned* __restrict__ bb)
{
    int t = threadIdx.x;
    if (t < 3) bb[t] = 0xFFFFFFFFu;
    else if (t < 6) bb[t] = 0u;
}

__global__ __launch_bounds__(256) void bbox_kernel(
    const float* __restrict__ x, unsigned* __restrict__ bb, int n)
{
    int i = blockIdx.x * 256 + threadIdx.x;
    unsigned emin[3], emax[3];
#pragma unroll
    for (int a = 0; a < 3; ++a) { unsigned e = encf(x[i * 3 + a]); emin[a] = e; emax[a] = e; }
#pragma unroll
    for (int o = 32; o; o >>= 1) {
#pragma unroll
        for (int a = 0; a < 3; ++a) {
            emin[a] = min(emin[a], (unsigned)__shfl_xor((int)emin[a], o, 64));
            emax[a] = max(emax[a], (unsigned)__shfl_xor((int)emax[a], o, 64));
        }
    }
    if ((threadIdx.x & 63) == 0) {
#pragma unroll
        for (int a = 0; a < 3; ++a) {
            atomicMin(&bb[a], emin[a]);
            atomicMax(&bb[3 + a], emax[a]);
        }
    }
}

__global__ __launch_bounds__(256) void hist_kernel(
    const float* __restrict__ x, const unsigned* __restrict__ bb,
    unsigned* __restrict__ counts, unsigned long long* __restrict__ rowmask, int n)
{
    int i = blockIdx.x * 256 + threadIdx.x;
    float mnx = decf(bb[0]), mny = decf(bb[1]), mnz = decf(bb[2]);
    float ivx = (float)G / (decf(bb[3]) - mnx);
    float ivy = (float)G / (decf(bb[4]) - mny);
    float ivz = (float)G / (decf(bb[5]) - mnz);
    int cx = cellc(x[i * 3 + 0], mnx, ivx);
    int cy = cellc(x[i * 3 + 1], mny, ivy);
    int cz = cellc(x[i * 3 + 2], mnz, ivz);
    atomicAdd(&counts[(cz * G + cy) * G + cx], 1u);
    atomicOr(&rowmask[cz * G + cy], 1ull << cx);
}

__global__ __launch_bounds__(256) void scan1_kernel(
    const unsigned* __restrict__ counts, unsigned* __restrict__ offs,
    unsigned* __restrict__ bsums)
{
    __shared__ unsigned s[256];
    int b = blockIdx.x, t = threadIdx.x;
    unsigned base = (unsigned)b * 1024 + t * 4;
    unsigned v[4], sum = 0;
#pragma unroll
    for (int k = 0; k < 4; ++k) { v[k] = counts[base + k]; sum += v[k]; }
    s[t] = sum; __syncthreads();
    for (int off = 1; off < 256; off <<= 1) {
        unsigned xv = (t >= off) ? s[t - off] : 0u;
        __syncthreads();
        s[t] += xv;
        __syncthreads();
    }
    unsigned excl = s[t] - sum;
    if (t == 255) bsums[b] = s[255];
    unsigned run = excl;
#pragma unroll
    for (int k = 0; k < 4; ++k) { offs[base + k] = run; run += v[k]; }
}

__global__ __launch_bounds__(256) void scan2_kernel(unsigned* __restrict__ bsums)
{
    __shared__ unsigned s[256];
    int t = threadIdx.x;
    unsigned v = bsums[t];
    s[t] = v; __syncthreads();
    for (int off = 1; off < 256; off <<= 1) {
        unsigned xv = (t >= off) ? s[t - off] : 0u;
        __syncthreads();
        s[t] += xv;
        __syncthreads();
    }
    bsums[t] = s[t] - v;
}

__global__ __launch_bounds__(256) void scan3_kernel(
    unsigned* __restrict__ offs, const unsigned* __restrict__ bsums,
    unsigned* __restrict__ cursors, int n)
{
    int b = blockIdx.x, t = threadIdx.x;
    unsigned add = bsums[b];
    unsigned base = (unsigned)b * 1024 + t * 4;
#pragma unroll
    for (int k = 0; k < 4; ++k) {
        unsigned v = offs[base + k] + add;
        offs[base + k] = v;
        cursors[base + k] = v;
    }
    if (b == 255 && t == 255) offs[NCELLS] = (unsigned)n;
}

// scatter also builds inverse permutation orig -> sorted position
__global__ __launch_bounds__(256) void scatter_kernel(
    const float* __restrict__ x, const unsigned* __restrict__ bb,
    unsigned* __restrict__ cursors, float4* __restrict__ sorted,
    unsigned* __restrict__ inv, int n)
{
    int i = blockIdx.x * 256 + threadIdx.x;
    float mnx = decf(bb[0]), mny = decf(bb[1]), mnz = decf(bb[2]);
    float ivx = (float)G / (decf(bb[3]) - mnx);
    float ivy = (float)G / (decf(bb[4]) - mny);
    float ivz = (float)G / (decf(bb[5]) - mnz);
    float x0 = x[i * 3 + 0], x1 = x[i * 3 + 1], x2 = x[i * 3 + 2];
    int cx = cellc(x0, mnx, ivx);
    int cy = cellc(x1, mny, ivy);
    int cz = cellc(x2, mnz, ivz);
    unsigned pos = atomicAdd(&cursors[(cz * G + cy) * G + cx], 1u);
    sorted[pos] = make_float4(x0, x1, x2, __int_as_float(i));
    inv[i] = pos;
}

// ---- grid kNN: wave/query, sub-row lane split + union bounds + brute --------
__global__ __launch_bounds__(256) void knn_grid_kernel(
    const float4* __restrict__ sorted, const unsigned* __restrict__ offs,
    const unsigned long long* __restrict__ rowmask,
    const unsigned* __restrict__ bb, const float* __restrict__ x,
    const unsigned* __restrict__ inv,
    unsigned short* __restrict__ knn, float* __restrict__ relf, int n)
{
    const int tid = threadIdx.x;
    const int l = tid & 63;                     // lane in wave
    const int nb = gridDim.x;
    const int b = blockIdx.x;
    const int fb = (b & 1) ? (nb - 1 - (b >> 1)) : (b >> 1);  // fold: ends first
    const int p = fb * 4 + (tid >> 6);          // query = sorted index

    float mnx = decf(bb[0]), mny = decf(bb[1]), mnz = decf(bb[2]);
    float mxx = decf(bb[3]), mxy = decf(bb[4]), mxz = decf(bb[5]);
    float hx = (mxx - mnx) / G, hy = (mxy - mny) / G, hz = (mxz - mnz) / G;
    float ivx = (float)G / (mxx - mnx);
    float ivy = (float)G / (mxy - mny);
    float ivz = (float)G / (mxz - mnz);

    float4 q = sorted[p];
    float xi = q.x, yi = q.y, zi = q.z;
    int iorig = __float_as_int(q.w);
    float sqi = fmaf(zi, zi, fmaf(yi, yi, xi * xi));
    int cx = cellc(xi, mnx, ivx), cy = cellc(yi, mny, ivy), cz = cellc(zi, mnz, ivz);
    float fx = (xi - mnx) - cx * hx;
    float fy = (yi - mny) - cy * hy;
    float fz = (zi - mnz) - cz * hz;

    DECL12; INIT12;
    float worst = 3.402823466e+38f;    // this lane's 12th-best distance
    float worst_g = 3.402823466e+38f;  // union upper bound

    auto waveMinWorst = [&]() -> float {
        float wm = worst;
        wm = fminf(wm, __shfl_xor(wm, 1, 64));
        wm = fminf(wm, __shfl_xor(wm, 2, 64));
        wm = fminf(wm, __shfl_xor(wm, 4, 64));
        wm = fminf(wm, __shfl_xor(wm, 8, 64));
        wm = fminf(wm, __shfl_xor(wm, 16, 64));
        wm = fminf(wm, __shfl_xor(wm, 32, 64));
        return wm;
    };

    // 12th smallest of the 64 per-lane minima (each a DISTINCT candidate,
    // so this is a valid upper bound on the union 12th distance).
    auto lane12Bound = [&]() -> float {
        float v = __int_as_float(__double2hiint(b0));
#pragma unroll
        for (int k = 2; k <= 64; k <<= 1) {
#pragma unroll
            for (int j = k >> 1; j >= 1; j >>= 1) {
                float pv = __shfl_xor(v, j, 64);
                bool dir = ((l & k) == 0);
                bool lower = ((l & j) == 0);
                float mn = fminf(v, pv), mx = fmaxf(v, pv);
                v = (lower == dir) ? mn : mx;
            }
        }
        return __shfl(v, 11, 64);
    };

    // serial scan with clamped prefetch (for rows owned by one lane)
    auto scanRange = [&](int c0, int c1) {
        unsigned j0 = offs[c0], j1 = offs[c1 + 1];
        if (j0 >= j1) return;
        float4 c = sorted[j0];
        for (unsigned t = j0; t < j1; ++t) {
            unsigned tn = (t + 1 < j1) ? t + 1 : t;
            float4 nx = sorted[tn];
            float sqj = fmaf(c.z, c.z, fmaf(c.y, c.y, c.x * c.x));
            float dot = fmaf(zi, c.z, fmaf(yi, c.y, xi * c.x));
            float d = fmaf(-2.0f, dot, sqi + sqj);
            int jg = __float_as_int(c.w);
            if (d <= fminf(worst, worst_g) && jg != iorig) {
                d = fmaxf(d, 0.0f);
                double key = __hiloint2double(__float_as_int(d), jg);
                INSERT12(key);
                worst = __int_as_float(__double2hiint(b11));
            }
            c = nx;
        }
    };

    // strided scan: this lane takes candidates sub, sub+step, ... of the range
    auto scanStrided = [&](int c0, int c1, int sub, int step) {
        unsigned j0 = offs[c0], j1 = offs[c1 + 1];
        for (unsigned t = j0 + sub; t < j1; t += step) {
            float4 c = sorted[t];
            float sqj = fmaf(c.z, c.z, fmaf(c.y, c.y, c.x * c.x));
            float dot = fmaf(zi, c.z, fmaf(yi, c.y, xi * c.x));
            float d = fmaf(-2.0f, dot, sqi + sqj);
            int jg = __float_as_int(c.w);
            if (d <= fminf(worst, worst_g) && jg != iorig) {
                d = fmaxf(d, 0.0f);
                double key = __hiloint2double(__float_as_int(d), jg);
                INSERT12(key);
                worst = __int_as_float(__double2hiint(b11));
            }
        }
    };

    // process one ring row (dz,dy known); sub/step partition within the row
    auto doRow = [&](int s, int dz, int dy, int sub, int step) {
        int zz = cz + dz, yy = cy + dy;
        if (zz < 0 || zz >= G || yy < 0 || yy >= G) return;
        int row = zz * G + yy;
        unsigned long long rm = rowmask[row];
        if (rm == 0ull) return;
        int rb = row * G;
        int adz = dz < 0 ? -dz : dz, ady = dy < 0 ? -dy : dy;
        if (adz == s || ady == s) {
            int x0 = max(cx - s, 0), x1 = min(cx + s, G - 1);
            unsigned long long msk =
                ((x1 == 63) ? ~0ull : ((1ull << (x1 + 1)) - 1ull)) &
                ~((1ull << x0) - 1ull);
            unsigned long long mm = rm & msk;
            if (mm) {
                int c0 = __ffsll((unsigned long long)mm) - 1;
                int c1 = 63 - __clzll((long long)mm);
                if (step == 1) scanRange(rb + c0, rb + c1);
                else           scanStrided(rb + c0, rb + c1, sub, step);
            }
        } else {
            int xm = cx - s, xp = cx + s;
            if (xm >= 0 && ((rm >> xm) & 1ull)) {
                if (step == 1) scanRange(rb + xm, rb + xm);
                else           scanStrided(rb + xm, rb + xm, sub, step);
            }
            if (xp < G && ((rm >> xp) & 1ull)) {
                if (step == 1) scanRange(rb + xp, rb + xp);
                else           scanStrided(rb + xp, rb + xp, sub, step);
            }
        }
    };

    bool done = false;
    for (int s = 0; s <= SMAX; ++s) {
        if (s > 0) {
            float bx = (s - 1) * hx + fminf(fx, hx - fx);
            float by = (s - 1) * hy + fminf(fy, hy - fy);
            float bz = (s - 1) * hz + fminf(fz, hz - fz);
            float bnd = fminf(bx, fminf(by, bz));
            float bnd2 = bnd * bnd;
            worst_g = fminf(worst_g, waveMinWorst());            // cheapest
            if (bnd2 > worst_g + 1e-4f) { done = true; break; }
            worst_g = fminf(worst_g, lane12Bound());             // cheap tight
            if (bnd2 > worst_g + 1e-4f) { done = true; break; }
            if (s >= 2) {                                        // exact union
                worst_g = fminf(worst_g,
                    wave_union_d12(b0,b1,b2,b3,b4,b5,b6,b7,b8,b9,b10,b11));
                if (bnd2 > worst_g + 1e-4f) { done = true; break; }
            }
        }
        if (s == 0) {
            int row = cz * G + cy;
            if ((rowmask[row] >> cx) & 1ull) {
                int rb = row * G;
                scanStrided(rb + cx, rb + cx, l, 64);  // all 64 lanes
            }
        } else {
            int w2 = 2 * s + 1;
            int nrows = w2 * w2;
            int lpr = 64 / nrows;                 // lanes per row (>=1 for s<=3)
            if (lpr > 1) {
                int r = l / lpr, sub = l - r * lpr;
                if (r < nrows) {
                    int dz = r / w2 - s, dy = r - (r / w2) * w2 - s;
                    doRow(s, dz, dy, sub, lpr);
                }
            } else {
                float rcp = 1.0f / (float)w2;
                for (int r = l; r < nrows; r += 64) {
                    int qd = (int)((float)r * rcp);
                    int rem = r - qd * w2;
                    if (rem < 0) { qd--; rem += w2; }
                    else if (rem >= w2) { qd++; rem -= w2; }
                    doRow(s, qd - s, rem - s, 0, 1);
                }
            }
        }
    }
    if (!done) {  // final certification after shells 0..SMAX
        float bx = SMAX * hx + fminf(fx, hx - fx);
        float by = SMAX * hy + fminf(fy, hy - fy);
        float bz = SMAX * hz + fminf(fz, hz - fz);
        float bnd = fminf(bx, fminf(by, bz));
        float bnd2 = bnd * bnd;
        worst_g = fminf(worst_g, waveMinWorst());
        if (bnd2 > worst_g + 1e-4f) done = true;
        if (!done) {
            worst_g = fminf(worst_g, lane12Bound());
            if (bnd2 > worst_g + 1e-4f) done = true;
        }
        if (!done) {
            worst_g = fminf(worst_g,
                wave_union_d12(b0,b1,b2,b3,b4,b5,b6,b7,b8,b9,b10,b11));
            if (bnd2 > worst_g + 1e-4f) done = true;
        }
    }
    if (!done) {
        // brute force: reset lists (avoid duplicate keys) but KEEP worst_g —
        // it is a valid upper bound on the true d12, so brute inserts fire
        // only for candidates inside the final radius.
        INIT12;
        worst = 3.402823466e+38f;
        for (int base = 0; base < n; base += 512) {
            float4 cc[8];
#pragma unroll
            for (int r = 0; r < 8; ++r) cc[r] = sorted[base + l + r * 64];
#pragma unroll
            for (int r = 0; r < 8; ++r) {
                float4 c = cc[r];
                float sqj = fmaf(c.z, c.z, fmaf(c.y, c.y, c.x * c.x));
                float dot = fmaf(zi, c.z, fmaf(yi, c.y, xi * c.x));
                float d = fmaf(-2.0f, dot, sqi + sqj);
                int jg = __float_as_int(c.w);
                if (d <= fminf(worst, worst_g) && jg != iorig) {
                    d = fmaxf(d, 0.0f);
                    double key = __hiloint2double(__float_as_int(d), jg);
                    INSERT12(key);
                    worst = __int_as_float(__double2hiint(b11));
                }
            }
        }
    }

    // ---- exact final merge of 64 sorted-12 lists ----
#pragma unroll
    for (int m = 1; m <= 32; m <<= 1) MERGE_STAGE(m)

    if (l == 0) {
        int idx[KNN];
        idx[0]=__double2loint(b0);  idx[1]=__double2loint(b1);  idx[2]=__double2loint(b2);
        idx[3]=__double2loint(b3);  idx[4]=__double2loint(b4);  idx[5]=__double2loint(b5);
        idx[6]=__double2loint(b6);  idx[7]=__double2loint(b7);  idx[8]=__double2loint(b8);
        idx[9]=__double2loint(b9);  idx[10]=__double2loint(b10); idx[11]=__double2loint(b11);

        float rx[KNN], ry[KNN], rz[KNN];
        float sx = 0.f, sy = 0.f, sz = 0.f;
#pragma unroll
        for (int s = 0; s < KNN; ++s) {
            int j = idx[s];                       // original index (tie-break key)
            knn[(size_t)p * KNN + s] = (unsigned short)inv[j];  // sorted position
            rx[s] = x[(size_t)j * 3 + 0] - xi;
            ry[s] = x[(size_t)j * 3 + 1] - yi;
            rz[s] = x[(size_t)j * 3 + 2] - zi;
            sx += rx[s]; sy += ry[s]; sz += rz[s];
        }
        float mx = sx / 12.0f, my = sy / 12.0f, mz = sz / 12.0f;
        float vx = 0.f, vy = 0.f, vz = 0.f;
#pragma unroll
        for (int s = 0; s < KNN; ++s) {
            float dx = rx[s] - mx, dy = ry[s] - my, dz = rz[s] - mz;
            vx += dx * dx; vy += dy * dy; vz += dz * dz;
        }
        float* rr = relf + (size_t)p * 8;
        rr[0] = mx; rr[1] = my; rr[2] = mz;
        rr[3] = sqrtf(vx / 12.0f); rr[4] = sqrtf(vy / 12.0f); rr[5] = sqrtf(vz / 12.0f);
        rr[6] = 0.0f; rr[7] = 0.0f;
    }
}

// ---------------- GEMM + silu (+FiLM): 64x192 tile, 4x12 micro, 256 thr ------
// Round-11 structure + fused neighbor-mean A-staging, BK=32 (half the
// barriers of BK=16; same waves/block and blocks/CU).
template <bool LAYER>
__global__ __launch_bounds__(256) void gemm_silu_kernel(
    const float* __restrict__ A0, const unsigned short* __restrict__ knnp,
    const float* __restrict__ Rel,
    const float* __restrict__ W, const float* __restrict__ bias,
    const float* __restrict__ gamma, const float* __restrict__ beta,
    float* __restrict__ out)
{
    __shared__ float As[32][68];
    __shared__ float Bs[32][196];
    const int tid = threadIdx.x;
    const int ty = tid >> 4, tx = tid & 15;
    const int m0 = blockIdx.x * 64;
    const int arow = tid >> 2, akoff = (tid & 3) * 8;  // A: 8 consecutive k
    const int bk = tid >> 4,  bc = (tid & 15) * 12;    // B rows bk, bk+16

    float acc[4][12] = {};
    const int NCH = LAYER ? 12 : 2;

    auto loadA = [&](int ch, float4& r0, float4& r1) {
        int k0 = ch * 32;
        if (!LAYER) {
            const float* src = &A0[(size_t)(m0 + arow) * 64 + k0 + akoff];
            r0 = *(const float4*)&src[0];
            r1 = *(const float4*)&src[4];
        } else if (k0 < 192) {
            const float* src = &A0[(size_t)(m0 + arow) * 192 + k0 + akoff];
            r0 = *(const float4*)&src[0];
            r1 = *(const float4*)&src[4];
        } else {
            // fused neighbor-mean: both f4 columns in one pass, j-ascending
            int c4 = (k0 - 192 + akoff) >> 2;
            const unsigned short* kn = knnp + (size_t)(m0 + arow) * KNN;
            const float4* h4 = (const float4*)A0;
            float4 s0 = make_float4(0.f, 0.f, 0.f, 0.f);
            float4 s1 = make_float4(0.f, 0.f, 0.f, 0.f);
#pragma unroll
            for (int j = 0; j < KNN; ++j) {
                const float4* bp2 = &h4[(size_t)kn[j] * 48 + c4];
                float4 v0 = bp2[0], v1 = bp2[1];
                s0.x += v0.x; s0.y += v0.y; s0.z += v0.z; s0.w += v0.w;
                s1.x += v1.x; s1.y += v1.y; s1.z += v1.z; s1.w += v1.w;
            }
            const float r = 1.0f / 12.0f;
            r0 = make_float4(s0.x * r, s0.y * r, s0.z * r, s0.w * r);
            r1 = make_float4(s1.x * r, s1.y * r, s1.z * r, s1.w * r);
        }
    };

    float4 ra0, ra1;
    loadA(0, ra0, ra1);
    const float* w0p = &W[(size_t)bk * 192 + bc];
    const float* w1p = &W[(size_t)(bk + 16) * 192 + bc];
    float4 rb0 = *(const float4*)&w0p[0], rb1 = *(const float4*)&w0p[4], rb2 = *(const float4*)&w0p[8];
    float4 rb3 = *(const float4*)&w1p[0], rb4 = *(const float4*)&w1p[4], rb5 = *(const float4*)&w1p[8];

    for (int ch = 0; ch < NCH; ++ch) {
        As[akoff + 0][arow] = ra0.x; As[akoff + 1][arow] = ra0.y;
        As[akoff + 2][arow] = ra0.z; As[akoff + 3][arow] = ra0.w;
        As[akoff + 4][arow] = ra1.x; As[akoff + 5][arow] = ra1.y;
        As[akoff + 6][arow] = ra1.z; As[akoff + 7][arow] = ra1.w;
        *(float4*)&Bs[bk][bc + 0] = rb0;
        *(float4*)&Bs[bk][bc + 4] = rb1;
        *(float4*)&Bs[bk][bc + 8] = rb2;
        *(float4*)&Bs[bk + 16][bc + 0] = rb3;
        *(float4*)&Bs[bk + 16][bc + 4] = rb4;
        *(float4*)&Bs[bk + 16][bc + 8] = rb5;
        __syncthreads();
        if (ch + 1 < NCH) {
            loadA(ch + 1, ra0, ra1);
            const float* wn0 = &W[(size_t)((ch + 1) * 32 + bk) * 192 + bc];
            const float* wn1 = &W[(size_t)((ch + 1) * 32 + bk + 16) * 192 + bc];
            rb0 = *(const float4*)&wn0[0]; rb1 = *(const float4*)&wn0[4]; rb2 = *(const float4*)&wn0[8];
            rb3 = *(const float4*)&wn1[0]; rb4 = *(const float4*)&wn1[4]; rb5 = *(const float4*)&wn1[8];
        }
#pragma unroll
        for (int k = 0; k < 32; ++k) {
            float4 a0 = *(const float4*)&As[k][ty * 4];
            float av[4] = {a0.x, a0.y, a0.z, a0.w};
            float4 q0 = *(const float4*)&Bs[k][tx * 12 + 0];
            float4 q1 = *(const float4*)&Bs[k][tx * 12 + 4];
            float4 q2 = *(const float4*)&Bs[k][tx * 12 + 8];
            float bv[12] = {q0.x, q0.y, q0.z, q0.w, q1.x, q1.y, q1.z, q1.w,
                            q2.x, q2.y, q2.z, q2.w};
#pragma unroll
            for (int a = 0; a < 4; ++a)
#pragma unroll
                for (int bcol = 0; bcol < 12; ++bcol)
                    acc[a][bcol] = fmaf(av[a], bv[bcol], acc[a][bcol]);
        }
        __syncthreads();
    }

    if (LAYER) {  // tail: k = 384..391 from relf8 (cols 6,7 zero)
        {
            int row = tid >> 2, cp = (tid & 3) * 2;
            float2 v = *(const float2*)&Rel[(size_t)(m0 + row) * 8 + cp];
            As[cp + 0][row] = v.x; As[cp + 1][row] = v.y;
        }
        {
            int k2 = tid >> 4, c = (tid & 15) * 12;
            if (k2 < 8) {
                int gk = 384 + k2; if (gk > 389) gk = 389;  // A rows 6,7 are 0
                const float* wr = &W[(size_t)gk * 192 + c];
                *(float4*)&Bs[k2][c + 0] = *(const float4*)&wr[0];
                *(float4*)&Bs[k2][c + 4] = *(const float4*)&wr[4];
                *(float4*)&Bs[k2][c + 8] = *(const float4*)&wr[8];
            }
        }
        __syncthreads();
#pragma unroll
        for (int k = 0; k < 8; ++k) {
            float4 a0 = *(const float4*)&As[k][ty * 4];
            float av[4] = {a0.x, a0.y, a0.z, a0.w};
            float4 q0 = *(const float4*)&Bs[k][tx * 12 + 0];
            float4 q1 = *(const float4*)&Bs[k][tx * 12 + 4];
            float4 q2 = *(const float4*)&Bs[k][tx * 12 + 8];
            float bv[12] = {q0.x, q0.y, q0.z, q0.w, q1.x, q1.y, q1.z, q1.w,
                            q2.x, q2.y, q2.z, q2.w};
#pragma unroll
            for (int a = 0; a < 4; ++a)
#pragma unroll
                for (int bcol = 0; bcol < 12; ++bcol)
                    acc[a][bcol] = fmaf(av[a], bv[bcol], acc[a][bcol]);
        }
        __syncthreads();
    }

#pragma unroll
    for (int a = 0; a < 4; ++a) {
        int gi = m0 + ty * 4 + a;
        float res[12];
#pragma unroll
        for (int bcol = 0; bcol < 12; ++bcol) {
            int gc = tx * 12 + bcol;
            float v = acc[a][bcol] + bias[gc];
            float s = 1.0f / (1.0f + expf(-v));
            v = v * s;
            if (LAYER) v = v * gamma[gc] + beta[gc];
            res[bcol] = v;
        }
        float* orow = &out[(size_t)gi * 192 + tx * 12];
        *(float4*)&orow[0] = make_float4(res[0], res[1], res[2], res[3]);
        *(float4*)&orow[4] = make_float4(res[4], res[5], res[6], res[7]);
        *(float4*)&orow[8] = make_float4(res[8], res[9], res[10], res[11]);
    }
}

// ---------------- output head (scatter to original order) --------------------
__global__ __launch_bounds__(256) void out_kernel(
    const float4* __restrict__ h4, const float4* __restrict__ sorted,
    const float* __restrict__ Wout, const float* __restrict__ bout,
    float* __restrict__ out, int n)
{
    __shared__ float w[576];
    int t = threadIdx.x;
    for (int e = t; e < 576; e += 256) w[e] = Wout[e];
    __syncthreads();
    int i = blockIdx.x * 256 + t;
    float a0 = 0.f, a1 = 0.f, a2 = 0.f;
    for (int k4 = 0; k4 < 48; ++k4) {
        float4 hv = h4[(size_t)i * 48 + k4];
        int k = k4 * 4;
        a0 = fmaf(hv.x, w[k * 3 + 0], a0); a1 = fmaf(hv.x, w[k * 3 + 1], a1); a2 = fmaf(hv.x, w[k * 3 + 2], a2);
        a0 = fmaf(hv.y, w[k * 3 + 3], a0); a1 = fmaf(hv.y, w[k * 3 + 4], a1); a2 = fmaf(hv.y, w[k * 3 + 5], a2);
        a0 = fmaf(hv.z, w[k * 3 + 6], a0); a1 = fmaf(hv.z, w[k * 3 + 7], a1); a2 = fmaf(hv.z, w[k * 3 + 8], a2);
        a0 = fmaf(hv.w, w[k * 3 + 9], a0); a1 = fmaf(hv.w, w[k * 3 + 10], a1); a2 = fmaf(hv.w, w[k * 3 + 11], a2);
    }
    int iorig = __float_as_int(sorted[i].w);
    out[(size_t)iorig * 3 + 0] = (a0 + bout[0]) * 0.01f;
    out[(size_t)iorig * 3 + 1] = (a1 + bout[1]) * 0.01f;
    out[(size_t)iorig * 3 + 2] = (a2 + bout[2]) * 0.01f;
}

// ---------------- launch ------------------------------------------------------
extern "C" void kernel_launch(void* const* d_in, const int* in_sizes, int n_in,
                              void* d_out, int out_size, void* d_ws, size_t ws_size,
                              hipStream_t stream)
{
    const float* x    = (const float*)d_in[0];
    const float* z    = (const float*)d_in[1];
    const float* B0   = (const float*)d_in[2];
    const float* B1   = (const float*)d_in[3];
    const float* B2   = (const float*)d_in[4];
    const float* Wp   = (const float*)d_in[5];
    const float* bp   = (const float*)d_in[6];
    const float* Wl   = (const float*)d_in[7];
    const float* bl   = (const float*)d_in[8];
    const float* Wg   = (const float*)d_in[9];
    const float* bg   = (const float*)d_in[10];
    const float* Wb   = (const float*)d_in[11];
    const float* bb   = (const float*)d_in[12];
    const float* Wout = (const float*)d_in[13];
    const float* bout = (const float*)d_in[14];

    int n = in_sizes[0] / 3;  // 32768

    // workspace layout (float offsets)
    float* ws = (float*)d_ws;
    float* bias0  = ws;                    // 192
    float* gammaB = ws + 192;              // 768
    float* betaB  = ws + 960;              // 768
    size_t off = 1728;
    unsigned short* knn = (unsigned short*)(ws + off);  off += (size_t)n * 6;  // 12n u16
    float* relf = ws + off;                off += (size_t)n * 8;
    float4* sorted = (float4*)(ws + off);  off += (size_t)n * 4;  // persistent
    float* hA   = ws + off;                off += (size_t)n * 192;
    float* hB   = ws + off;                off += (size_t)n * 192;

    // grid scratch aliases inside hA (dead before gemm0 writes hA):
    unsigned* bbx     = (unsigned*)hA;              // 8 (6 used)
    unsigned* counts  = bbx + 8;                    // NCELLS
    unsigned* offsA   = counts + NCELLS;            // NCELLS + 1
    unsigned* cursors = offsA + NCELLS + 1;         // NCELLS
    unsigned* bsums   = cursors + NCELLS;           // 256
    size_t gu = 8 + (size_t)NCELLS * 3 + 1 + 256;
    gu = (gu + 1) & ~(size_t)1;                     // 8B align for u64
    unsigned long long* rowmask = (unsigned long long*)((unsigned*)hA + gu);  // G*G u64
    gu += (size_t)G * G * 2;
    unsigned* inv = (unsigned*)hA + gu;             // n u32 (orig -> sorted pos)
    float* pe = hB;

    init_bbox_kernel<<<1, 64, 0, stream>>>(bbx);
    hipMemsetAsync(counts, 0, (size_t)NCELLS * 4, stream);
    hipMemsetAsync(rowmask, 0, (size_t)G * G * 8, stream);
    precompute_kernel<<<1, 256, 0, stream>>>(z, Wp, bp, Wg, bg, Wb, bb,
                                             bias0, gammaB, betaB);
    bbox_kernel<<<n / 256, 256, 0, stream>>>(x, bbx, n);
    hist_kernel<<<n / 256, 256, 0, stream>>>(x, bbx, counts, rowmask, n);
    scan1_kernel<<<NCELLS / 1024, 256, 0, stream>>>(counts, offsA, bsums);
    scan2_kernel<<<1, 256, 0, stream>>>(bsums);
    scan3_kernel<<<NCELLS / 1024, 256, 0, stream>>>(offsA, bsums, cursors, n);
    scatter_kernel<<<n / 256, 256, 0, stream>>>(x, bbx, cursors, sorted, inv, n);
    prep_kernel<<<n / 256, 256, 0, stream>>>(sorted, B0, B1, B2, pe, n);
    knn_grid_kernel<<<n / 4, 256, 0, stream>>>(sorted, offsA, rowmask, bbx, x,
                                               inv, knn, relf, n);

    gemm_silu_kernel<false><<<n / 64, 256, 0, stream>>>(
        pe, nullptr, nullptr, Wp, bias0, nullptr, nullptr, hA);

    float* hcur = hA;
    float* hnxt = hB;
    for (int li = 0; li < 4; ++li) {
        gemm_silu_kernel<true><<<n / 64, 256, 0, stream>>>(
            hcur, knn, relf,
            Wl + (size_t)li * 390 * 192, bl + (size_t)li * 192,
            gammaB + (size_t)li * 192, betaB + (size_t)li * 192, hnxt);
        float* t = hcur; hcur = hnxt; hnxt = t;
    }

    out_kernel<<<n / 256, 256, 0, stream>>>((const float4*)hcur, sorted,
                                            Wout, bout, (float*)d_out, n);
}

// Round 19
// 769.752 us; speedup vs baseline: 1.0604x; 1.0604x over previous
//
#include <hip/hip_runtime.h>
#include <math.h>

#define WIDTH 192
#define KNN 12
#define G 64
#define NCELLS (G * G * G)
#define SMAX 8

// ---------- sorted-12 list of (d,idx) packed as positive doubles ----------
#define CE(a, b) { double _lo = fmin(a, b); double _hi = fmax(a, b); a = _lo; b = _hi; }
#define INSERT12(key) { \
    b11 = fmin(b11, key); \
    CE(b10, b11); CE(b9, b10); CE(b8, b9); CE(b7, b8); CE(b6, b7); \
    CE(b5, b6);  CE(b4, b5); CE(b3, b4); CE(b2, b3); CE(b1, b2); CE(b0, b1); }
#define DECL12 double b0,b1,b2,b3,b4,b5,b6,b7,b8,b9,b10,b11
#define INIT12 { b0=__hiloint2double(0x7F7FFFFF,0);  b1=__hiloint2double(0x7F7FFFFF,1); \
    b2=__hiloint2double(0x7F7FFFFF,2);  b3=__hiloint2double(0x7F7FFFFF,3); \
    b4=__hiloint2double(0x7F7FFFFF,4);  b5=__hiloint2double(0x7F7FFFFF,5); \
    b6=__hiloint2double(0x7F7FFFFF,6);  b7=__hiloint2double(0x7F7FFFFF,7); \
    b8=__hiloint2double(0x7F7FFFFF,8);  b9=__hiloint2double(0x7F7FFFFF,9); \
    b10=__hiloint2double(0x7F7FFFFF,10); b11=__hiloint2double(0x7F7FFFFF,11); }

// butterfly merge stage (verified BM16 network, virtual +inf padding)
#define MERGE_STAGE(m) { \
    double pb11 = shflx_d(b11, m), pb10 = shflx_d(b10, m), pb9 = shflx_d(b9, m); \
    double pb8  = shflx_d(b8, m),  pb7  = shflx_d(b7, m),  pb6 = shflx_d(b6, m); \
    double pb5  = shflx_d(b5, m),  pb4  = shflx_d(b4, m),  pb3 = shflx_d(b3, m); \
    double pb2  = shflx_d(b2, m),  pb1  = shflx_d(b1, m),  pb0 = shflx_d(b0, m); \
    double c12 = pb3, c13 = pb2, c14 = pb1, c15 = pb0; \
    b4 = fmin(b4, pb11); b5 = fmin(b5, pb10); b6 = fmin(b6, pb9);  b7 = fmin(b7, pb8); \
    b8 = fmin(b8, pb7);  b9 = fmin(b9, pb6);  b10 = fmin(b10, pb5); b11 = fmin(b11, pb4); \
    CE(b0, b8);  CE(b1, b9);  CE(b2, b10); CE(b3, b11); \
    CE(b4, c12); CE(b5, c13); CE(b6, c14); CE(b7, c15); \
    CE(b0, b4);  CE(b1, b5);  CE(b2, b6);  CE(b3, b7); \
    CE(b8, c12); CE(b9, c13); CE(b10, c14); CE(b11, c15); \
    CE(b0, b2);  CE(b1, b3);  CE(b4, b6);  CE(b5, b7); \
    CE(b8, b10); CE(b9, b11); \
    CE(b0, b1);  CE(b2, b3);  CE(b4, b5);  CE(b6, b7); \
    CE(b8, b9);  CE(b10, b11); }

__device__ inline unsigned encf(float f) {
    unsigned u = __float_as_uint(f);
    return (u & 0x80000000u) ? ~u : (u | 0x80000000u);
}
__device__ inline float decf(unsigned u) {
    return (u & 0x80000000u) ? __uint_as_float(u & 0x7fffffffu) : __uint_as_float(~u);
}
__device__ inline int cellc(float v, float mn, float invh) {
    int c = (int)((v - mn) * invh);
    return min(max(c, 0), G - 1);
}
__device__ inline double shflx_d(double v, int m) {
    int lo = __shfl_xor(__double2loint(v), m, 64);
    int hi = __shfl_xor(__double2hiint(v), m, 64);
    return __hiloint2double(hi, lo);
}

// exact union 12th-best across the wave (on copies; all lanes agree)
__device__ inline float wave_union_d12(
    double b0, double b1, double b2, double b3, double b4, double b5,
    double b6, double b7, double b8, double b9, double b10, double b11)
{
#pragma unroll
    for (int m = 1; m <= 32; m <<= 1) MERGE_STAGE(m)
    return __int_as_float(__double2hiint(b11));
}

// ---------------- prep: padded Fourier PE (sorted order) ---------------------
__global__ __launch_bounds__(256) void prep_kernel(
    const float4* __restrict__ sorted, const float* __restrict__ B0,
    const float* __restrict__ B1, const float* __restrict__ B2,
    float* __restrict__ pe, int n)
{
    int i = blockIdx.x * 256 + threadIdx.x;
    float4 q = sorted[i];
    float x0 = q.x, x1 = q.y, x2 = q.z;
    const float* Bm[3] = {B0, B1, B2};
    float* pr = pe + (size_t)i * 64;
#pragma unroll
    for (int m = 0; m < 3; ++m) {
        const float* B = Bm[m];
#pragma unroll
        for (int k = 0; k < 8; ++k) {
            float arg = x0 * B[k] + x1 * B[8 + k] + x2 * B[16 + k];
            pr[m * 16 + k]     = sinf(arg);
            pr[m * 16 + 8 + k] = cosf(arg);
        }
    }
    pr[48] = x0; pr[49] = x1; pr[50] = x2;
#pragma unroll
    for (int c = 51; c < 64; ++c) pr[c] = 0.0f;
}

// ---------------- precompute: fold z into biases -----------------------------
__global__ __launch_bounds__(256) void precompute_kernel(
    const float* __restrict__ z, const float* __restrict__ Wp, const float* __restrict__ bp,
    const float* __restrict__ Wg, const float* __restrict__ bg,
    const float* __restrict__ Wb, const float* __restrict__ bb,
    float* __restrict__ bias0, float* __restrict__ gammaB, float* __restrict__ betaB)
{
    __shared__ float zs[64];
    int t = threadIdx.x;
    if (t < 64) zs[t] = z[t];
    __syncthreads();
    if (t < WIDTH) {
        float acc = bp[t];
        for (int k = 0; k < 64; ++k) acc += zs[k] * Wp[(51 + k) * WIDTH + t];
        bias0[t] = acc;
        for (int l = 0; l < 4; ++l) {
            float g = bg[l * WIDTH + t];
            float b = bb[l * WIDTH + t];
            for (int k = 0; k < 64; ++k) {
                g += zs[k] * Wg[(l * 64 + k) * WIDTH + t];
                b += zs[k] * Wb[(l * 64 + k) * WIDTH + t];
            }
            gammaB[l * WIDTH + t] = g;
            betaB[l * WIDTH + t] = b;
        }
    }
}

// ---------------- grid build -------------------------------------------------
__global__ __launch_bounds__(64) void init_bbox_kernel(unsigned* __restrict__ bb)
{
    int t = threadIdx.x;
    if (t < 3) bb[t] = 0xFFFFFFFFu;
    else if (t < 6) bb[t] = 0u;
}

__global__ __launch_bounds__(256) void bbox_kernel(
    const float* __restrict__ x, unsigned* __restrict__ bb, int n)
{
    int i = blockIdx.x * 256 + threadIdx.x;
    unsigned emin[3], emax[3];
#pragma unroll
    for (int a = 0; a < 3; ++a) { unsigned e = encf(x[i * 3 + a]); emin[a] = e; emax[a] = e; }
#pragma unroll
    for (int o = 32; o; o >>= 1) {
#pragma unroll
        for (int a = 0; a < 3; ++a) {
            emin[a] = min(emin[a], (unsigned)__shfl_xor((int)emin[a], o, 64));
            emax[a] = max(emax[a], (unsigned)__shfl_xor((int)emax[a], o, 64));
        }
    }
    if ((threadIdx.x & 63) == 0) {
#pragma unroll
        for (int a = 0; a < 3; ++a) {
            atomicMin(&bb[a], emin[a]);
            atomicMax(&bb[3 + a], emax[a]);
        }
    }
}

__global__ __launch_bounds__(256) void hist_kernel(
    const float* __restrict__ x, const unsigned* __restrict__ bb,
    unsigned* __restrict__ counts, unsigned long long* __restrict__ rowmask, int n)
{
    int i = blockIdx.x * 256 + threadIdx.x;
    float mnx = decf(bb[0]), mny = decf(bb[1]), mnz = decf(bb[2]);
    float ivx = (float)G / (decf(bb[3]) - mnx);
    float ivy = (float)G / (decf(bb[4]) - mny);
    float ivz = (float)G / (decf(bb[5]) - mnz);
    int cx = cellc(x[i * 3 + 0], mnx, ivx);
    int cy = cellc(x[i * 3 + 1], mny, ivy);
    int cz = cellc(x[i * 3 + 2], mnz, ivz);
    atomicAdd(&counts[(cz * G + cy) * G + cx], 1u);
    atomicOr(&rowmask[cz * G + cy], 1ull << cx);
}

__global__ __launch_bounds__(256) void scan1_kernel(
    const unsigned* __restrict__ counts, unsigned* __restrict__ offs,
    unsigned* __restrict__ bsums)
{
    __shared__ unsigned s[256];
    int b = blockIdx.x, t = threadIdx.x;
    unsigned base = (unsigned)b * 1024 + t * 4;
    unsigned v[4], sum = 0;
#pragma unroll
    for (int k = 0; k < 4; ++k) { v[k] = counts[base + k]; sum += v[k]; }
    s[t] = sum; __syncthreads();
    for (int off = 1; off < 256; off <<= 1) {
        unsigned xv = (t >= off) ? s[t - off] : 0u;
        __syncthreads();
        s[t] += xv;
        __syncthreads();
    }
    unsigned excl = s[t] - sum;
    if (t == 255) bsums[b] = s[255];
    unsigned run = excl;
#pragma unroll
    for (int k = 0; k < 4; ++k) { offs[base + k] = run; run += v[k]; }
}

__global__ __launch_bounds__(256) void scan2_kernel(unsigned* __restrict__ bsums)
{
    __shared__ unsigned s[256];
    int t = threadIdx.x;
    unsigned v = bsums[t];
    s[t] = v; __syncthreads();
    for (int off = 1; off < 256; off <<= 1) {
        unsigned xv = (t >= off) ? s[t - off] : 0u;
        __syncthreads();
        s[t] += xv;
        __syncthreads();
    }
    bsums[t] = s[t] - v;
}

__global__ __launch_bounds__(256) void scan3_kernel(
    unsigned* __restrict__ offs, const unsigned* __restrict__ bsums,
    unsigned* __restrict__ cursors, int n)
{
    int b = blockIdx.x, t = threadIdx.x;
    unsigned add = bsums[b];
    unsigned base = (unsigned)b * 1024 + t * 4;
#pragma unroll
    for (int k = 0; k < 4; ++k) {
        unsigned v = offs[base + k] + add;
        offs[base + k] = v;
        cursors[base + k] = v;
    }
    if (b == 255 && t == 255) offs[NCELLS] = (unsigned)n;
}

// scatter also builds inverse permutation orig -> sorted position
__global__ __launch_bounds__(256) void scatter_kernel(
    const float* __restrict__ x, const unsigned* __restrict__ bb,
    unsigned* __restrict__ cursors, float4* __restrict__ sorted,
    unsigned* __restrict__ inv, int n)
{
    int i = blockIdx.x * 256 + threadIdx.x;
    float mnx = decf(bb[0]), mny = decf(bb[1]), mnz = decf(bb[2]);
    float ivx = (float)G / (decf(bb[3]) - mnx);
    float ivy = (float)G / (decf(bb[4]) - mny);
    float ivz = (float)G / (decf(bb[5]) - mnz);
    float x0 = x[i * 3 + 0], x1 = x[i * 3 + 1], x2 = x[i * 3 + 2];
    int cx = cellc(x0, mnx, ivx);
    int cy = cellc(x1, mny, ivy);
    int cz = cellc(x2, mnz, ivz);
    unsigned pos = atomicAdd(&cursors[(cz * G + cy) * G + cx], 1u);
    sorted[pos] = make_float4(x0, x1, x2, __int_as_float(i));
    inv[i] = pos;
}

// ---- grid kNN: wave/query, sub-row lane split + union bounds + brute --------
__global__ __launch_bounds__(256) void knn_grid_kernel(
    const float4* __restrict__ sorted, const unsigned* __restrict__ offs,
    const unsigned long long* __restrict__ rowmask,
    const unsigned* __restrict__ bb, const float* __restrict__ x,
    const unsigned* __restrict__ inv,
    unsigned short* __restrict__ knn, float* __restrict__ relf, int n)
{
    const int tid = threadIdx.x;
    const int l = tid & 63;                     // lane in wave
    const int nb = gridDim.x;
    const int b = blockIdx.x;
    const int fb = (b & 1) ? (nb - 1 - (b >> 1)) : (b >> 1);  // fold: ends first
    const int p = fb * 4 + (tid >> 6);          // query = sorted index

    float mnx = decf(bb[0]), mny = decf(bb[1]), mnz = decf(bb[2]);
    float mxx = decf(bb[3]), mxy = decf(bb[4]), mxz = decf(bb[5]);
    float hx = (mxx - mnx) / G, hy = (mxy - mny) / G, hz = (mxz - mnz) / G;
    float ivx = (float)G / (mxx - mnx);
    float ivy = (float)G / (mxy - mny);
    float ivz = (float)G / (mxz - mnz);

    float4 q = sorted[p];
    float xi = q.x, yi = q.y, zi = q.z;
    int iorig = __float_as_int(q.w);
    float sqi = fmaf(zi, zi, fmaf(yi, yi, xi * xi));
    int cx = cellc(xi, mnx, ivx), cy = cellc(yi, mny, ivy), cz = cellc(zi, mnz, ivz);
    float fx = (xi - mnx) - cx * hx;
    float fy = (yi - mny) - cy * hy;
    float fz = (zi - mnz) - cz * hz;

    DECL12; INIT12;
    float worst = 3.402823466e+38f;    // this lane's 12th-best distance
    float worst_g = 3.402823466e+38f;  // union upper bound

    auto waveMinWorst = [&]() -> float {
        float wm = worst;
        wm = fminf(wm, __shfl_xor(wm, 1, 64));
        wm = fminf(wm, __shfl_xor(wm, 2, 64));
        wm = fminf(wm, __shfl_xor(wm, 4, 64));
        wm = fminf(wm, __shfl_xor(wm, 8, 64));
        wm = fminf(wm, __shfl_xor(wm, 16, 64));
        wm = fminf(wm, __shfl_xor(wm, 32, 64));
        return wm;
    };

    // 12th smallest of the 64 per-lane minima (each a DISTINCT candidate,
    // so this is a valid upper bound on the union 12th distance).
    auto lane12Bound = [&]() -> float {
        float v = __int_as_float(__double2hiint(b0));
#pragma unroll
        for (int k = 2; k <= 64; k <<= 1) {
#pragma unroll
            for (int j = k >> 1; j >= 1; j >>= 1) {
                float pv = __shfl_xor(v, j, 64);
                bool dir = ((l & k) == 0);
                bool lower = ((l & j) == 0);
                float mn = fminf(v, pv), mx = fmaxf(v, pv);
                v = (lower == dir) ? mn : mx;
            }
        }
        return __shfl(v, 11, 64);
    };

    // serial scan with clamped prefetch (for rows owned by one lane)
    auto scanRange = [&](int c0, int c1) {
        unsigned j0 = offs[c0], j1 = offs[c1 + 1];
        if (j0 >= j1) return;
        float4 c = sorted[j0];
        for (unsigned t = j0; t < j1; ++t) {
            unsigned tn = (t + 1 < j1) ? t + 1 : t;
            float4 nx = sorted[tn];
            float sqj = fmaf(c.z, c.z, fmaf(c.y, c.y, c.x * c.x));
            float dot = fmaf(zi, c.z, fmaf(yi, c.y, xi * c.x));
            float d = fmaf(-2.0f, dot, sqi + sqj);
            int jg = __float_as_int(c.w);
            if (d <= fminf(worst, worst_g) && jg != iorig) {
                d = fmaxf(d, 0.0f);
                double key = __hiloint2double(__float_as_int(d), jg);
                INSERT12(key);
                worst = __int_as_float(__double2hiint(b11));
            }
            c = nx;
        }
    };

    // strided scan: this lane takes candidates sub, sub+step, ... of the range
    auto scanStrided = [&](int c0, int c1, int sub, int step) {
        unsigned j0 = offs[c0], j1 = offs[c1 + 1];
        for (unsigned t = j0 + sub; t < j1; t += step) {
            float4 c = sorted[t];
            float sqj = fmaf(c.z, c.z, fmaf(c.y, c.y, c.x * c.x));
            float dot = fmaf(zi, c.z, fmaf(yi, c.y, xi * c.x));
            float d = fmaf(-2.0f, dot, sqi + sqj);
            int jg = __float_as_int(c.w);
            if (d <= fminf(worst, worst_g) && jg != iorig) {
                d = fmaxf(d, 0.0f);
                double key = __hiloint2double(__float_as_int(d), jg);
                INSERT12(key);
                worst = __int_as_float(__double2hiint(b11));
            }
        }
    };

    // process one ring row (dz,dy known); sub/step partition within the row
    auto doRow = [&](int s, int dz, int dy, int sub, int step) {
        int zz = cz + dz, yy = cy + dy;
        if (zz < 0 || zz >= G || yy < 0 || yy >= G) return;
        int row = zz * G + yy;
        unsigned long long rm = rowmask[row];
        if (rm == 0ull) return;
        int rb = row * G;
        int adz = dz < 0 ? -dz : dz, ady = dy < 0 ? -dy : dy;
        if (adz == s || ady == s) {
            int x0 = max(cx - s, 0), x1 = min(cx + s, G - 1);
            unsigned long long msk =
                ((x1 == 63) ? ~0ull : ((1ull << (x1 + 1)) - 1ull)) &
                ~((1ull << x0) - 1ull);
            unsigned long long mm = rm & msk;
            if (mm) {
                int c0 = __ffsll((unsigned long long)mm) - 1;
                int c1 = 63 - __clzll((long long)mm);
                if (step == 1) scanRange(rb + c0, rb + c1);
                else           scanStrided(rb + c0, rb + c1, sub, step);
            }
        } else {
            int xm = cx - s, xp = cx + s;
            if (xm >= 0 && ((rm >> xm) & 1ull)) {
                if (step == 1) scanRange(rb + xm, rb + xm);
                else           scanStrided(rb + xm, rb + xm, sub, step);
            }
            if (xp < G && ((rm >> xp) & 1ull)) {
                if (step == 1) scanRange(rb + xp, rb + xp);
                else           scanStrided(rb + xp, rb + xp, sub, step);
            }
        }
    };

    bool done = false;
    for (int s = 0; s <= SMAX; ++s) {
        if (s > 0) {
            float bx = (s - 1) * hx + fminf(fx, hx - fx);
            float by = (s - 1) * hy + fminf(fy, hy - fy);
            float bz = (s - 1) * hz + fminf(fz, hz - fz);
            float bnd = fminf(bx, fminf(by, bz));
            float bnd2 = bnd * bnd;
            worst_g = fminf(worst_g, waveMinWorst());            // cheapest
            if (bnd2 > worst_g + 1e-4f) { done = true; break; }
            worst_g = fminf(worst_g, lane12Bound());             // cheap tight
            if (bnd2 > worst_g + 1e-4f) { done = true; break; }
            if (s >= 2) {                                        // exact union
                worst_g = fminf(worst_g,
                    wave_union_d12(b0,b1,b2,b3,b4,b5,b6,b7,b8,b9,b10,b11));
                if (bnd2 > worst_g + 1e-4f) { done = true; break; }
            }
        }
        if (s == 0) {
            int row = cz * G + cy;
            if ((rowmask[row] >> cx) & 1ull) {
                int rb = row * G;
                scanStrided(rb + cx, rb + cx, l, 64);  // all 64 lanes
            }
        } else {
            int w2 = 2 * s + 1;
            int nrows = w2 * w2;
            int lpr = 64 / nrows;                 // lanes per row (>=1 for s<=3)
            if (lpr > 1) {
                int r = l / lpr, sub = l - r * lpr;
                if (r < nrows) {
                    int dz = r / w2 - s, dy = r - (r / w2) * w2 - s;
                    doRow(s, dz, dy, sub, lpr);
                }
            } else {
                float rcp = 1.0f / (float)w2;
                for (int r = l; r < nrows; r += 64) {
                    int qd = (int)((float)r * rcp);
                    int rem = r - qd * w2;
                    if (rem < 0) { qd--; rem += w2; }
                    else if (rem >= w2) { qd++; rem -= w2; }
                    doRow(s, qd - s, rem - s, 0, 1);
                }
            }
        }
    }
    if (!done) {  // final certification after shells 0..SMAX
        float bx = SMAX * hx + fminf(fx, hx - fx);
        float by = SMAX * hy + fminf(fy, hy - fy);
        float bz = SMAX * hz + fminf(fz, hz - fz);
        float bnd = fminf(bx, fminf(by, bz));
        float bnd2 = bnd * bnd;
        worst_g = fminf(worst_g, waveMinWorst());
        if (bnd2 > worst_g + 1e-4f) done = true;
        if (!done) {
            worst_g = fminf(worst_g, lane12Bound());
            if (bnd2 > worst_g + 1e-4f) done = true;
        }
        if (!done) {
            worst_g = fminf(worst_g,
                wave_union_d12(b0,b1,b2,b3,b4,b5,b6,b7,b8,b9,b10,b11));
            if (bnd2 > worst_g + 1e-4f) done = true;
        }
    }
    if (!done) {
        // brute force: reset lists (avoid duplicate keys) but KEEP worst_g —
        // it is a valid upper bound on the true d12, so brute inserts fire
        // only for candidates inside the final radius.
        INIT12;
        worst = 3.402823466e+38f;
        for (int base = 0; base < n; base += 512) {
            float4 cc[8];
#pragma unroll
            for (int r = 0; r < 8; ++r) cc[r] = sorted[base + l + r * 64];
#pragma unroll
            for (int r = 0; r < 8; ++r) {
                float4 c = cc[r];
                float sqj = fmaf(c.z, c.z, fmaf(c.y, c.y, c.x * c.x));
                float dot = fmaf(zi, c.z, fmaf(yi, c.y, xi * c.x));
                float d = fmaf(-2.0f, dot, sqi + sqj);
                int jg = __float_as_int(c.w);
                if (d <= fminf(worst, worst_g) && jg != iorig) {
                    d = fmaxf(d, 0.0f);
                    double key = __hiloint2double(__float_as_int(d), jg);
                    INSERT12(key);
                    worst = __int_as_float(__double2hiint(b11));
                }
            }
        }
    }

    // ---- exact final merge of 64 sorted-12 lists ----
#pragma unroll
    for (int m = 1; m <= 32; m <<= 1) MERGE_STAGE(m)

    if (l == 0) {
        int idx[KNN];
        idx[0]=__double2loint(b0);  idx[1]=__double2loint(b1);  idx[2]=__double2loint(b2);
        idx[3]=__double2loint(b3);  idx[4]=__double2loint(b4);  idx[5]=__double2loint(b5);
        idx[6]=__double2loint(b6);  idx[7]=__double2loint(b7);  idx[8]=__double2loint(b8);
        idx[9]=__double2loint(b9);  idx[10]=__double2loint(b10); idx[11]=__double2loint(b11);

        float rx[KNN], ry[KNN], rz[KNN];
        float sx = 0.f, sy = 0.f, sz = 0.f;
#pragma unroll
        for (int s = 0; s < KNN; ++s) {
            int j = idx[s];                       // original index (tie-break key)
            knn[(size_t)p * KNN + s] = (unsigned short)inv[j];  // sorted position
            rx[s] = x[(size_t)j * 3 + 0] - xi;
            ry[s] = x[(size_t)j * 3 + 1] - yi;
            rz[s] = x[(size_t)j * 3 + 2] - zi;
            sx += rx[s]; sy += ry[s]; sz += rz[s];
        }
        float mx = sx / 12.0f, my = sy / 12.0f, mz = sz / 12.0f;
        float vx = 0.f, vy = 0.f, vz = 0.f;
#pragma unroll
        for (int s = 0; s < KNN; ++s) {
            float dx = rx[s] - mx, dy = ry[s] - my, dz = rz[s] - mz;
            vx += dx * dx; vy += dy * dy; vz += dz * dz;
        }
        float* rr = relf + (size_t)p * 8;
        rr[0] = mx; rr[1] = my; rr[2] = mz;
        rr[3] = sqrtf(vx / 12.0f); rr[4] = sqrtf(vy / 12.0f); rr[5] = sqrtf(vz / 12.0f);
        rr[6] = 0.0f; rr[7] = 0.0f;
    }
}

// ---------------- GEMM + silu (+FiLM): 64x192 tile, 4x12 micro, 256 thr ------
// Round-11 structure (BK=16, single buffer + register prefetch) + fused
// neighbor-mean A-staging (bit-identical to the old agg kernel). This K-loop
// shape is the empirical best of 6 variants tested — do not restructure.
template <bool LAYER>
__global__ __launch_bounds__(256) void gemm_silu_kernel(
    const float* __restrict__ A0, const unsigned short* __restrict__ knnp,
    const float* __restrict__ Rel,
    const float* __restrict__ W, const float* __restrict__ bias,
    const float* __restrict__ gamma, const float* __restrict__ beta,
    float* __restrict__ out)
{
    __shared__ float As[16][68];
    __shared__ float Bs[16][196];
    const int tid = threadIdx.x;
    const int ty = tid >> 4, tx = tid & 15;
    const int m0 = blockIdx.x * 64;
    const int arow = tid >> 2, akoff = (tid & 3) * 4;
    const int bk = tid >> 4,  bc = (tid & 15) * 12;

    float acc[4][12] = {};
    const int NCH = LAYER ? 24 : 4;

    auto loadA = [&](int ch) -> float4 {
        int k0 = ch * 16;
        if (!LAYER) {
            return *(const float4*)&A0[(size_t)(m0 + arow) * 64 + k0 + akoff];
        } else if (k0 < 192) {
            return *(const float4*)&A0[(size_t)(m0 + arow) * 192 + k0 + akoff];
        } else {
            int c4 = (k0 - 192 + akoff) >> 2;
            const unsigned short* kn = knnp + (size_t)(m0 + arow) * KNN;
            const float4* h4 = (const float4*)A0;
            float4 s = make_float4(0.f, 0.f, 0.f, 0.f);
#pragma unroll
            for (int j = 0; j < KNN; ++j) {
                float4 v = h4[(size_t)kn[j] * 48 + c4];
                s.x += v.x; s.y += v.y; s.z += v.z; s.w += v.w;
            }
            const float r = 1.0f / 12.0f;
            return make_float4(s.x * r, s.y * r, s.z * r, s.w * r);
        }
    };

    float4 ra = loadA(0);
    const float* wr0 = &W[(size_t)bk * 192 + bc];
    float4 rb0 = *(const float4*)&wr0[0];
    float4 rb1 = *(const float4*)&wr0[4];
    float4 rb2 = *(const float4*)&wr0[8];

    for (int ch = 0; ch < NCH; ++ch) {
        As[akoff + 0][arow] = ra.x; As[akoff + 1][arow] = ra.y;
        As[akoff + 2][arow] = ra.z; As[akoff + 3][arow] = ra.w;
        *(float4*)&Bs[bk][bc + 0] = rb0;
        *(float4*)&Bs[bk][bc + 4] = rb1;
        *(float4*)&Bs[bk][bc + 8] = rb2;
        __syncthreads();
        if (ch + 1 < NCH) {
            ra = loadA(ch + 1);
            const float* wr = &W[(size_t)((ch + 1) * 16 + bk) * 192 + bc];
            rb0 = *(const float4*)&wr[0];
            rb1 = *(const float4*)&wr[4];
            rb2 = *(const float4*)&wr[8];
        }
#pragma unroll
        for (int k = 0; k < 16; ++k) {
            float4 a0 = *(const float4*)&As[k][ty * 4];
            float av[4] = {a0.x, a0.y, a0.z, a0.w};
            float4 q0 = *(const float4*)&Bs[k][tx * 12 + 0];
            float4 q1 = *(const float4*)&Bs[k][tx * 12 + 4];
            float4 q2 = *(const float4*)&Bs[k][tx * 12 + 8];
            float bv[12] = {q0.x, q0.y, q0.z, q0.w, q1.x, q1.y, q1.z, q1.w,
                            q2.x, q2.y, q2.z, q2.w};
#pragma unroll
            for (int a = 0; a < 4; ++a)
#pragma unroll
                for (int bcol = 0; bcol < 12; ++bcol)
                    acc[a][bcol] = fmaf(av[a], bv[bcol], acc[a][bcol]);
        }
        __syncthreads();
    }

    if (LAYER) {  // tail: k = 384..391 from relf8 (cols 6,7 zero)
        {
            int row = tid >> 2, cp = (tid & 3) * 2;
            float2 v = *(const float2*)&Rel[(size_t)(m0 + row) * 8 + cp];
            As[cp + 0][row] = v.x; As[cp + 1][row] = v.y;
        }
        {
            int k2 = tid >> 4, c = (tid & 15) * 12;
            if (k2 < 8) {
                int gk = 384 + k2; if (gk > 389) gk = 389;  // A rows 6,7 are 0
                const float* wr = &W[(size_t)gk * 192 + c];
                *(float4*)&Bs[k2][c + 0] = *(const float4*)&wr[0];
                *(float4*)&Bs[k2][c + 4] = *(const float4*)&wr[4];
                *(float4*)&Bs[k2][c + 8] = *(const float4*)&wr[8];
            }
        }
        __syncthreads();
#pragma unroll
        for (int k = 0; k < 8; ++k) {
            float4 a0 = *(const float4*)&As[k][ty * 4];
            float av[4] = {a0.x, a0.y, a0.z, a0.w};
            float4 q0 = *(const float4*)&Bs[k][tx * 12 + 0];
            float4 q1 = *(const float4*)&Bs[k][tx * 12 + 4];
            float4 q2 = *(const float4*)&Bs[k][tx * 12 + 8];
            float bv[12] = {q0.x, q0.y, q0.z, q0.w, q1.x, q1.y, q1.z, q1.w,
                            q2.x, q2.y, q2.z, q2.w};
#pragma unroll
            for (int a = 0; a < 4; ++a)
#pragma unroll
                for (int bcol = 0; bcol < 12; ++bcol)
                    acc[a][bcol] = fmaf(av[a], bv[bcol], acc[a][bcol]);
        }
        __syncthreads();
    }

#pragma unroll
    for (int a = 0; a < 4; ++a) {
        int gi = m0 + ty * 4 + a;
        float res[12];
#pragma unroll
        for (int bcol = 0; bcol < 12; ++bcol) {
            int gc = tx * 12 + bcol;
            float v = acc[a][bcol] + bias[gc];
            float s = 1.0f / (1.0f + expf(-v));
            v = v * s;
            if (LAYER) v = v * gamma[gc] + beta[gc];
            res[bcol] = v;
        }
        float* orow = &out[(size_t)gi * 192 + tx * 12];
        *(float4*)&orow[0] = make_float4(res[0], res[1], res[2], res[3]);
        *(float4*)&orow[4] = make_float4(res[4], res[5], res[6], res[7]);
        *(float4*)&orow[8] = make_float4(res[8], res[9], res[10], res[11]);
    }
}

// ---------------- output head (scatter to original order) --------------------
__global__ __launch_bounds__(256) void out_kernel(
    const float4* __restrict__ h4, const float4* __restrict__ sorted,
    const float* __restrict__ Wout, const float* __restrict__ bout,
    float* __restrict__ out, int n)
{
    __shared__ float w[576];
    int t = threadIdx.x;
    for (int e = t; e < 576; e += 256) w[e] = Wout[e];
    __syncthreads();
    int i = blockIdx.x * 256 + t;
    float a0 = 0.f, a1 = 0.f, a2 = 0.f;
    for (int k4 = 0; k4 < 48; ++k4) {
        float4 hv = h4[(size_t)i * 48 + k4];
        int k = k4 * 4;
        a0 = fmaf(hv.x, w[k * 3 + 0], a0); a1 = fmaf(hv.x, w[k * 3 + 1], a1); a2 = fmaf(hv.x, w[k * 3 + 2], a2);
        a0 = fmaf(hv.y, w[k * 3 + 3], a0); a1 = fmaf(hv.y, w[k * 3 + 4], a1); a2 = fmaf(hv.y, w[k * 3 + 5], a2);
        a0 = fmaf(hv.z, w[k * 3 + 6], a0); a1 = fmaf(hv.z, w[k * 3 + 7], a1); a2 = fmaf(hv.z, w[k * 3 + 8], a2);
        a0 = fmaf(hv.w, w[k * 3 + 9], a0); a1 = fmaf(hv.w, w[k * 3 + 10], a1); a2 = fmaf(hv.w, w[k * 3 + 11], a2);
    }
    int iorig = __float_as_int(sorted[i].w);
    out[(size_t)iorig * 3 + 0] = (a0 + bout[0]) * 0.01f;
    out[(size_t)iorig * 3 + 1] = (a1 + bout[1]) * 0.01f;
    out[(size_t)iorig * 3 + 2] = (a2 + bout[2]) * 0.01f;
}

// ---------------- launch ------------------------------------------------------
extern "C" void kernel_launch(void* const* d_in, const int* in_sizes, int n_in,
                              void* d_out, int out_size, void* d_ws, size_t ws_size,
                              hipStream_t stream)
{
    const float* x    = (const float*)d_in[0];
    const float* z    = (const float*)d_in[1];
    const float* B0   = (const float*)d_in[2];
    const float* B1   = (const float*)d_in[3];
    const float* B2   = (const float*)d_in[4];
    const float* Wp   = (const float*)d_in[5];
    const float* bp   = (const float*)d_in[6];
    const float* Wl   = (const float*)d_in[7];
    const float* bl   = (const float*)d_in[8];
    const float* Wg   = (const float*)d_in[9];
    const float* bg   = (const float*)d_in[10];
    const float* Wb   = (const float*)d_in[11];
    const float* bb   = (const float*)d_in[12];
    const float* Wout = (const float*)d_in[13];
    const float* bout = (const float*)d_in[14];

    int n = in_sizes[0] / 3;  // 32768

    // workspace layout (float offsets)
    float* ws = (float*)d_ws;
    float* bias0  = ws;                    // 192
    float* gammaB = ws + 192;              // 768
    float* betaB  = ws + 960;              // 768
    size_t off = 1728;
    unsigned short* knn = (unsigned short*)(ws + off);  off += (size_t)n * 6;  // 12n u16
    float* relf = ws + off;                off += (size_t)n * 8;
    float4* sorted = (float4*)(ws + off);  off += (size_t)n * 4;  // persistent
    float* hA   = ws + off;                off += (size_t)n * 192;
    float* hB   = ws + off;                off += (size_t)n * 192;

    // grid scratch aliases inside hA (dead before gemm0 writes hA):
    unsigned* bbx     = (unsigned*)hA;              // 8 (6 used)
    unsigned* counts  = bbx + 8;                    // NCELLS
    unsigned* offsA   = counts + NCELLS;            // NCELLS + 1
    unsigned* cursors = offsA + NCELLS + 1;         // NCELLS
    unsigned* bsums   = cursors + NCELLS;           // 256
    size_t gu = 8 + (size_t)NCELLS * 3 + 1 + 256;
    gu = (gu + 1) & ~(size_t)1;                     // 8B align for u64
    unsigned long long* rowmask = (unsigned long long*)((unsigned*)hA + gu);  // G*G u64
    gu += (size_t)G * G * 2;
    unsigned* inv = (unsigned*)hA + gu;             // n u32 (orig -> sorted pos)
    float* pe = hB;

    init_bbox_kernel<<<1, 64, 0, stream>>>(bbx);
    hipMemsetAsync(counts, 0, (size_t)NCELLS * 4, stream);
    hipMemsetAsync(rowmask, 0, (size_t)G * G * 8, stream);
    precompute_kernel<<<1, 256, 0, stream>>>(z, Wp, bp, Wg, bg, Wb, bb,
                                             bias0, gammaB, betaB);
    bbox_kernel<<<n / 256, 256, 0, stream>>>(x, bbx, n);
    hist_kernel<<<n / 256, 256, 0, stream>>>(x, bbx, counts, rowmask, n);
    scan1_kernel<<<NCELLS / 1024, 256, 0, stream>>>(counts, offsA, bsums);
    scan2_kernel<<<1, 256, 0, stream>>>(bsums);
    scan3_kernel<<<NCELLS / 1024, 256, 0, stream>>>(offsA, bsums, cursors, n);
    scatter_kernel<<<n / 256, 256, 0, stream>>>(x, bbx, cursors, sorted, inv, n);
    prep_kernel<<<n / 256, 256, 0, stream>>>(sorted, B0, B1, B2, pe, n);
    knn_grid_kernel<<<n / 4, 256, 0, stream>>>(sorted, offsA, rowmask, bbx, x,
                                               inv, knn, relf, n);

    gemm_silu_kernel<false><<<n / 64, 256, 0, stream>>>(
        pe, nullptr, nullptr, Wp, bias0, nullptr, nullptr, hA);

    float* hcur = hA;
    float* hnxt = hB;
    for (int li = 0; li < 4; ++li) {
        gemm_silu_kernel<true><<<n / 64, 256, 0, stream>>>(
            hcur, knn, relf,
            Wl + (size_t)li * 390 * 192, bl + (size_t)li * 192,
            gammaB + (size_t)li * 192, betaB + (size_t)li * 192, hnxt);
        float* t = hcur; hcur = hnxt; hnxt = t;
    }

    out_kernel<<<n / 256, 256, 0, stream>>>((const float4*)hcur, sorted,
                                            Wout, bout, (float*)d_out, n);
}